// Round 7
// baseline (327.952 us; speedup 1.0000x reference)
//
#include <hip/hip_runtime.h>

typedef unsigned short u16;
typedef float f32x4 __attribute__((ext_vector_type(4)));
typedef short s16x8 __attribute__((ext_vector_type(8)));
typedef short s16x4 __attribute__((ext_vector_type(4)));

__device__ __forceinline__ u16 f2b(float f) {
  union { float f; unsigned u; } v; v.f = f;
  unsigned r = v.u + 0x7fffu + ((v.u >> 16) & 1u);
  return (u16)(r >> 16);
}
__device__ __forceinline__ float b2f(u16 b) {
  union { unsigned u; float f; } v; v.u = ((unsigned)b) << 16;
  return v.f;
}
__device__ __forceinline__ f32x4 mfma_bf16(s16x8 a, s16x8 b, f32x4 c) {
  return __builtin_amdgcn_mfma_f32_16x16x32_bf16(a, b, c, 0, 0, 0);
}
__device__ __forceinline__ void gl_lds16(const u16* g, u16* l) {
  __builtin_amdgcn_global_load_lds(
      (const __attribute__((address_space(1))) void*)g,
      (__attribute__((address_space(3))) void*)l, 16, 0, 0);
}

// ---------------------------------------------------------------------------
// x fp32 -> bf16, vectorized (8 elems/thread)
// ---------------------------------------------------------------------------
__global__ void conv_x(const float* __restrict__ in, u16* __restrict__ out, int n) {
  int i = (blockIdx.x * 256 + threadIdx.x) * 8;
  if (i >= n) return;
  f32x4 a = *(const f32x4*)(in + i);
  f32x4 b = *(const f32x4*)(in + i + 4);
  s16x8 o = {(short)f2b(a.x), (short)f2b(a.y), (short)f2b(a.z), (short)f2b(a.w),
             (short)f2b(b.x), (short)f2b(b.y), (short)f2b(b.z), (short)f2b(b.w)};
  *(s16x8*)(out + i) = o;
}

// ---------------------------------------------------------------------------
// Weight transpose+convert fp32->bf16, 64x64 tiles, vectorized.
// z=0: [Wq|Wk|Wv] cols -> WqkvT[3072][2048].  z=1: Wo -> WoT[2048][2048].
// ---------------------------------------------------------------------------
__global__ void transW(const float* __restrict__ Wq, const float* __restrict__ Wk,
                       const float* __restrict__ Wv, const float* __restrict__ Wo,
                       u16* __restrict__ WqkvT, u16* __restrict__ WoT) {
  __shared__ u16 tile[64][68];
  const int z = blockIdx.z;
  if (z == 1 && blockIdx.x >= 32) return;
  const int ox = blockIdx.x * 64;   // output-row base == source-col base
  const int oy = blockIdx.y * 64;   // source-row base
  const float* src; int scol, C; u16* dst;
  if (z == 0) {
    if (ox < 2048)      { src = Wq; scol = ox;        C = 2048; }
    else if (ox < 2560) { src = Wk; scol = ox - 2048; C = 512;  }
    else                { src = Wv; scol = ox - 2560; C = 512;  }
    dst = WqkvT;
  } else { src = Wo; scol = ox; C = 2048; dst = WoT; }
  const int t = threadIdx.x, lr = t >> 4, c4 = (t & 15) * 4;
#pragma unroll
  for (int p = 0; p < 4; ++p) {
    int r = p * 16 + lr;
    f32x4 v = *(const f32x4*)(src + (size_t)(oy + r) * C + scol + c4);
    s16x4 pk = {(short)f2b(v.x), (short)f2b(v.y), (short)f2b(v.z), (short)f2b(v.w)};
    *(s16x4*)(&tile[r][c4]) = pk;
  }
  __syncthreads();
#pragma unroll
  for (int q = 0; q < 4; ++q) {
    int oc = q * 16 + lr;
    s16x4 pk = {(short)tile[c4 + 0][oc], (short)tile[c4 + 1][oc],
                (short)tile[c4 + 2][oc], (short)tile[c4 + 3][oc]};
    *(s16x4*)(dst + (size_t)(ox + oc) * 2048 + oy + c4) = pk;
  }
}

// v slice of qkv (cols 2560..3071, stride 3072) -> vT[512][2048], bf16.
__global__ void transpose_v(const u16* __restrict__ qkv, u16* __restrict__ vT) {
  __shared__ u16 tile[64][68];
  const int bx = blockIdx.x * 64;   // v-col base (0..511)
  const int by = blockIdx.y * 64;   // token base
  const int t = threadIdx.x, lr = t >> 4, c4 = (t & 15) * 4;
#pragma unroll
  for (int p = 0; p < 4; ++p) {
    int r = p * 16 + lr;
    s16x4 v = *(const s16x4*)(qkv + (size_t)(by + r) * 3072 + 2560 + bx + c4);
    *(s16x4*)(&tile[r][c4]) = v;
  }
  __syncthreads();
#pragma unroll
  for (int q = 0; q < 4; ++q) {
    int oc = q * 16 + lr;
    s16x4 pk = {(short)tile[c4 + 0][oc], (short)tile[c4 + 1][oc],
                (short)tile[c4 + 2][oc], (short)tile[c4 + 3][oc]};
    *(s16x4*)(vT + (size_t)(bx + oc) * 2048 + by + c4) = pk;
  }
}

// ---------------------------------------------------------------------------
// QKV GEMM: qkv[2048][3072] = x[2048][2048] @ WqkvT^T, RoPE fused in epilogue.
// 64(M)x128(N) tile, BK=32, async global_load_lds staging.  grid (24,32).
// ---------------------------------------------------------------------------
__global__ __launch_bounds__(256, 2) void gemm_qkv(const u16* __restrict__ A,
                                                   const u16* __restrict__ Bt,
                                                   u16* __restrict__ C) {
  __shared__ __align__(16) u16 As[64 * 32];
  __shared__ __align__(16) u16 Bs[128 * 32];
  const int K = 2048;
  const int n0 = blockIdx.x * 128, m0 = blockIdx.y * 64;
  const int t = threadIdx.x, wave = t >> 6, lane = t & 63;
  const int quad = lane >> 4, lc = lane & 15;
  const int wm = (wave >> 1) * 32, wn = (wave & 1) * 64;
  const int arow = t >> 2, akc = (t & 3) * 8;

  const f32x4 z = {0.f, 0.f, 0.f, 0.f};
  f32x4 acc[2][4];
#pragma unroll
  for (int i = 0; i < 2; ++i)
#pragma unroll
    for (int j = 0; j < 4; ++j) acc[i][j] = z;

  for (int k0 = 0; k0 < K; k0 += 32) {
    gl_lds16(A  + (size_t)(m0 + arow) * K + k0 + akc, As + wave * 512);
    gl_lds16(Bt + (size_t)(n0 + arow) * K + k0 + akc, Bs + wave * 512);
    gl_lds16(Bt + (size_t)(n0 + 64 + arow) * K + k0 + akc, Bs + 2048 + wave * 512);
    __syncthreads();
    s16x8 af[2], bfr[4];
#pragma unroll
    for (int i = 0; i < 2; ++i)
      af[i] = *(const s16x8*)(As + (wm + i * 16 + lc) * 32 + quad * 8);
#pragma unroll
    for (int j = 0; j < 4; ++j)
      bfr[j] = *(const s16x8*)(Bs + (wn + j * 16 + lc) * 32 + quad * 8);
#pragma unroll
    for (int i = 0; i < 2; ++i)
#pragma unroll
      for (int j = 0; j < 4; ++j)
        acc[i][j] = mfma_bf16(af[i], bfr[j], acc[i][j]);
    __syncthreads();
  }
  // Epilogue + fused RoPE (cols < 2560 are q|k; interleaved pair = lanes lc^1)
#pragma unroll
  for (int j = 0; j < 4; ++j) {
    const int colbase = wn + j * 16;
    const bool rope = (n0 + colbase) < 2560;
    const int col = n0 + colbase + lc;
    const int ip = ((colbase + lc) & 127) >> 1;
    const float inv_freq = exp2f(-0.20762050593046014f * (float)ip);
#pragma unroll
    for (int i = 0; i < 2; ++i)
#pragma unroll
      for (int r = 0; r < 4; ++r) {
        float v = acc[i][j][r];
        float p = __shfl_xor(v, 1);
        float val = v;
        if (rope) {
          int token = m0 + wm + i * 16 + quad * 4 + r;
          float ang = (float)token * inv_freq;
          float sv, cv;
          sincosf(ang, &sv, &cv);
          val = (lc & 1) ? (p * sv + v * cv) : (v * cv - p * sv);
        }
        C[(size_t)(m0 + wm + i * 16 + quad * 4 + r) * 3072 + col] = f2b(val);
      }
  }
}

// ---------------------------------------------------------------------------
// Out GEMM: out_f32[2048][2048] = ctx[2048][2048] @ WoT^T.  64x128 tile.
// ---------------------------------------------------------------------------
__global__ __launch_bounds__(256, 2) void gemm_out(const u16* __restrict__ A,
                                                   const u16* __restrict__ Bt,
                                                   float* __restrict__ C) {
  __shared__ __align__(16) u16 As[64 * 32];
  __shared__ __align__(16) u16 Bs[128 * 32];
  const int K = 2048;
  const int n0 = blockIdx.x * 128, m0 = blockIdx.y * 64;
  const int t = threadIdx.x, wave = t >> 6, lane = t & 63;
  const int quad = lane >> 4, lc = lane & 15;
  const int wm = (wave >> 1) * 32, wn = (wave & 1) * 64;
  const int arow = t >> 2, akc = (t & 3) * 8;

  const f32x4 z = {0.f, 0.f, 0.f, 0.f};
  f32x4 acc[2][4];
#pragma unroll
  for (int i = 0; i < 2; ++i)
#pragma unroll
    for (int j = 0; j < 4; ++j) acc[i][j] = z;

  for (int k0 = 0; k0 < K; k0 += 32) {
    gl_lds16(A  + (size_t)(m0 + arow) * K + k0 + akc, As + wave * 512);
    gl_lds16(Bt + (size_t)(n0 + arow) * K + k0 + akc, Bs + wave * 512);
    gl_lds16(Bt + (size_t)(n0 + 64 + arow) * K + k0 + akc, Bs + 2048 + wave * 512);
    __syncthreads();
    s16x8 af[2], bfr[4];
#pragma unroll
    for (int i = 0; i < 2; ++i)
      af[i] = *(const s16x8*)(As + (wm + i * 16 + lc) * 32 + quad * 8);
#pragma unroll
    for (int j = 0; j < 4; ++j)
      bfr[j] = *(const s16x8*)(Bs + (wn + j * 16 + lc) * 32 + quad * 8);
#pragma unroll
    for (int i = 0; i < 2; ++i)
#pragma unroll
      for (int j = 0; j < 4; ++j)
        acc[i][j] = mfma_bf16(af[i], bfr[j], acc[i][j]);
    __syncthreads();
  }
#pragma unroll
  for (int i = 0; i < 2; ++i)
#pragma unroll
    for (int j = 0; j < 4; ++j)
#pragma unroll
      for (int r = 0; r < 4; ++r)
        C[(size_t)(m0 + wm + i * 16 + quad * 4 + r) * 2048 + n0 + wn + j * 16 + lc] =
            acc[i][j][r];
}

// ---------------------------------------------------------------------------
// Attention v3: K direct global->VGPR (no LDS), Q frags hoisted to regs,
// V LDS double-buffered with full-tile-ahead register prefetch, Ps wave-
// private, ONE __syncthreads per tile (vmcnt ~0 at the drain).
// grid (32 qt, 16 heads, 2 halves).  LDS 45 KB.
// ---------------------------------------------------------------------------
__global__ __launch_bounds__(256, 2) void attn_k(const u16* __restrict__ qkv,
                                                 const u16* __restrict__ vT,
                                                 u16* __restrict__ Opart,
                                                 float* __restrict__ Lpart) {
  const int qt = blockIdx.x, hq = blockIdx.y, half = blockIdx.z;
  const int kvh = hq & 3, sg = hq >> 2;
  const int qc0 = hq << 7, kc0 = 2048 + (kvh << 7), vr0 = kvh << 7;

  __shared__ __align__(16) u16 Vs[2][128 * 72];  // 36 KB (double buffer)
  __shared__ __align__(16) u16 Ps[64 * 72];      //  9 KB (wave-private rows)

  const int t = threadIdx.x, wave = t >> 6, lane = t & 63;
  const int quad = lane >> 4, lc = lane & 15;
  const int vr = t >> 3, vc = (t & 7) * 8;       // V-staging coords

  // Q A-frags hoisted once (rows qt*64 + wave*16 + lc; proven A-layout)
  s16x8 qf[4];
#pragma unroll
  for (int ks = 0; ks < 4; ++ks)
    qf[ks] = *(const s16x8*)(qkv + (size_t)(qt * 64 + wave * 16 + lc) * 3072 +
                             qc0 + ks * 32 + quad * 8);

  const f32x4 z = {0.f, 0.f, 0.f, 0.f};
  f32x4 oa[8];
#pragma unroll
  for (int n = 0; n < 8; ++n) oa[n] = z;
  float Ls[4] = {0.f, 0.f, 0.f, 0.f};
  const float scale2 = 0.12751744545f;  // 1/sqrt(128) * log2(e)
  const int qrow_base = qt * 64 + wave * 16 + quad * 4;

  const int ntiles = qt + 1, n0t = (ntiles + 1) >> 1;
  const int lo = half ? n0t : 0, hi = half ? ntiles : n0t;

  s16x8 vreg[4];
  if (lo < hi) {  // load + stage first V tile
    const int j0 = lo * 64;
#pragma unroll
    for (int p = 0; p < 4; ++p)
      vreg[p] = *(const s16x8*)(vT + (size_t)(vr0 + p * 32 + vr) * 2048 + j0 + vc);
#pragma unroll
    for (int p = 0; p < 4; ++p)
      *(s16x8*)(Vs[lo & 1] + (p * 32 + vr) * 72 + vc) = vreg[p];
  }
  __syncthreads();

  for (int tile = lo; tile < hi; ++tile) {
    const int j0 = tile * 64;
    // prefetch V(t+1): in flight across this entire tile's compute
    if (tile + 1 < hi) {
#pragma unroll
      for (int p = 0; p < 4; ++p)
        vreg[p] = *(const s16x8*)(vT + (size_t)(vr0 + p * 32 + vr) * 2048 +
                                  j0 + 64 + vc);
    }
    // QK: K B-frags direct global->VGPR (16B contiguous per lane, L2-resident)
    s16x8 kf[16];
#pragma unroll
    for (int ks = 0; ks < 4; ++ks)
#pragma unroll
      for (int n = 0; n < 4; ++n)
        kf[ks * 4 + n] = *(const s16x8*)(qkv + (size_t)(j0 + n * 16 + lc) * 3072 +
                                         kc0 + ks * 32 + quad * 8);
    f32x4 sa[4];
#pragma unroll
    for (int n = 0; n < 4; ++n) sa[n] = z;
#pragma unroll
    for (int ks = 0; ks < 4; ++ks)
#pragma unroll
      for (int n = 0; n < 4; ++n)
        sa[n] = mfma_bf16(qf[ks], kf[ks * 4 + n], sa[n]);
    // mask + exp2 + Ps write (wave-private rows) + row-sum partials
#pragma unroll
    for (int n = 0; n < 4; ++n) {
      int jc = j0 + n * 16 + lc;
#pragma unroll
      for (int r = 0; r < 4; ++r) {
        float e = (jc <= qrow_base + r) ? exp2f(sa[n][r] * scale2) : 0.f;
        Ps[(wave * 16 + quad * 4 + r) * 72 + n * 16 + lc] = f2b(e);
        Ls[r] += e;
      }
    }
    // O += P V  (Ps rows wave-private; Vs current buffer)
    const u16* Vb = Vs[tile & 1];
#pragma unroll
    for (int ks = 0; ks < 2; ++ks) {
      s16x8 af = *(const s16x8*)(Ps + (wave * 16 + lc) * 72 + ks * 32 + quad * 8);
#pragma unroll
      for (int n = 0; n < 8; ++n) {
        s16x8 bf = *(const s16x8*)(Vb + (n * 16 + lc) * 72 + ks * 32 + quad * 8);
        oa[n] = mfma_bf16(af, bf, oa[n]);
      }
    }
    // stage V(t+1) into the other buffer (vmcnt wait on vreg: already arrived)
    if (tile + 1 < hi) {
#pragma unroll
      for (int p = 0; p < 4; ++p)
        *(s16x8*)(Vs[(tile + 1) & 1] + (p * 32 + vr) * 72 + vc) = vreg[p];
    }
    __syncthreads();   // drain is cheap: vmcnt consumed by the ds_writes above
  }
  // quad-wide row-sum reduce (raw sum; combine kernel divides)
#pragma unroll
  for (int r = 0; r < 4; ++r) {
    float s = Ls[r];
    s += __shfl_xor(s, 1);
    s += __shfl_xor(s, 2);
    s += __shfl_xor(s, 4);
    s += __shfl_xor(s, 8);
    Ls[r] = s;
  }
  const size_t tbase = (size_t)(half * 16 + hq) * 32 + qt;
  u16* Ob = Opart + tbase * (64 * 128);
  if (lc == 0) {
#pragma unroll
    for (int r = 0; r < 4; ++r)
      Lpart[tbase * 64 + wave * 16 + quad * 4 + r] = Ls[r];
  }
#pragma unroll
  for (int n = 0; n < 8; ++n)
#pragma unroll
    for (int r = 0; r < 4; ++r)
      Ob[(wave * 16 + quad * 4 + r) * 128 + n * 16 + lc] = f2b(oa[n][r]);
}

// Combine halves: ctx = (O0+O1)/(L0+L1), write bf16 at out-head slot kv*4+sg.
__global__ void attn_combine(const u16* __restrict__ Opart,
                             const float* __restrict__ Lpart,
                             u16* __restrict__ ctx) {
  const int hq = blockIdx.y, kvh = hq & 3, sg = hq >> 2;
  const int lin = blockIdx.x * 256 + threadIdx.x;   // 0..32767
  const int token = lin >> 4, d8 = (lin & 15) << 3;
  const int qt = token >> 6, row = token & 63;
  const size_t t0 = (size_t)hq * 32 + qt, t1 = t0 + 512;
  const u16* O0 = Opart + t0 * 8192 + row * 128 + d8;
  const u16* O1 = Opart + t1 * 8192 + row * 128 + d8;
  const float inv = 1.f / (Lpart[t0 * 64 + row] + Lpart[t1 * 64 + row]);
  s16x8 a = *(const s16x8*)O0, b = *(const s16x8*)O1;
  s16x8 o;
#pragma unroll
  for (int i = 0; i < 8; ++i)
    o[i] = (short)f2b((b2f((u16)a[i]) + b2f((u16)b[i])) * inv);
  *(s16x8*)(ctx + (size_t)token * 2048 + ((kvh * 4 + sg) << 7) + d8) = o;
}

// ---------------------------------------------------------------------------
extern "C" void kernel_launch(void* const* d_in, const int* in_sizes, int n_in,
                              void* d_out, int out_size, void* d_ws, size_t ws_size,
                              hipStream_t stream) {
  const float* x  = (const float*)d_in[0];
  const float* Wq = (const float*)d_in[1];
  const float* Wk = (const float*)d_in[2];
  const float* Wv = (const float*)d_in[3];
  const float* Wo = (const float*)d_in[4];

  char* w = (char*)d_ws;
  u16* xb     = (u16*)w;  w += (size_t)2048 * 2048 * 2;   //  8 MB
  u16* WqkvT  = (u16*)w;  w += (size_t)3072 * 2048 * 2;   // 12 MB
  u16* WoT    = (u16*)w;  w += (size_t)2048 * 2048 * 2;   //  8 MB
  u16* qkvb   = (u16*)w;  w += (size_t)2048 * 3072 * 2;   // 12 MB
  u16* vTb    = (u16*)w;  w += (size_t)512 * 2048 * 2;    //  2 MB
  u16* ctxb   = (u16*)w;  w += (size_t)2048 * 2048 * 2;   //  8 MB
  float* Lpart= (float*)w; w += (size_t)2 * 16 * 32 * 64 * 4;  // 256 KB
  // Opart (16 MB) aliases xb+WqkvT (20 MB) — both dead before attn_k runs.
  u16* Opart  = (u16*)d_ws;

  // 1) convert x, transpose+convert weights
  conv_x<<<2048, 256, 0, stream>>>(x, xb, 2048 * 2048);
  transW<<<dim3(48, 32, 2), 256, 0, stream>>>(Wq, Wk, Wv, Wo, WqkvT, WoT);

  // 2) fused QKV projection + RoPE epilogue
  gemm_qkv<<<dim3(24, 32), 256, 0, stream>>>(xb, WqkvT, qkvb);

  // 3) v -> vT for the PV MFMA B-operand
  transpose_v<<<dim3(8, 32), 256, 0, stream>>>(qkvb, vTb);

  // 4) split-K attention (v3) + combine
  attn_k<<<dim3(32, 16, 2), 256, 0, stream>>>(qkvb, vTb, Opart, Lpart);
  attn_combine<<<dim3(128, 16), 256, 0, stream>>>(Opart, Lpart, ctxb);

  // 5) output projection (fp32 out)
  gemm_out<<<dim3(16, 32), 256, 0, stream>>>(ctxb, WoT, (float*)d_out);
}

// Round 8
// 253.209 us; speedup vs baseline: 1.2952x; 1.2952x over previous
//
#include <hip/hip_runtime.h>

typedef unsigned short u16;
typedef float f32x4 __attribute__((ext_vector_type(4)));
typedef short s16x8 __attribute__((ext_vector_type(8)));
typedef short s16x4 __attribute__((ext_vector_type(4)));

__device__ __forceinline__ u16 f2b(float f) {
  union { float f; unsigned u; } v; v.f = f;
  unsigned r = v.u + 0x7fffu + ((v.u >> 16) & 1u);
  return (u16)(r >> 16);
}
__device__ __forceinline__ float b2f(u16 b) {
  union { unsigned u; float f; } v; v.u = ((unsigned)b) << 16;
  return v.f;
}
__device__ __forceinline__ f32x4 mfma_bf16(s16x8 a, s16x8 b, f32x4 c) {
  return __builtin_amdgcn_mfma_f32_16x16x32_bf16(a, b, c, 0, 0, 0);
}
__device__ __forceinline__ void gl_lds16(const u16* g, u16* l) {
  __builtin_amdgcn_global_load_lds(
      (const __attribute__((address_space(1))) void*)g,
      (__attribute__((address_space(3))) void*)l, 16, 0, 0);
}

// ---------------------------------------------------------------------------
// x fp32 -> bf16, vectorized (8 elems/thread)
// ---------------------------------------------------------------------------
__global__ void conv_x(const float* __restrict__ in, u16* __restrict__ out, int n) {
  int i = (blockIdx.x * 256 + threadIdx.x) * 8;
  if (i >= n) return;
  f32x4 a = *(const f32x4*)(in + i);
  f32x4 b = *(const f32x4*)(in + i + 4);
  s16x8 o = {(short)f2b(a.x), (short)f2b(a.y), (short)f2b(a.z), (short)f2b(a.w),
             (short)f2b(b.x), (short)f2b(b.y), (short)f2b(b.z), (short)f2b(b.w)};
  *(s16x8*)(out + i) = o;
}

// ---------------------------------------------------------------------------
// Weight transpose+convert fp32->bf16, 64x64 tiles, vectorized.
// z=0: [Wq|Wk|Wv] cols -> WqkvT[3072][2048].  z=1: Wo -> WoT[2048][2048].
// ---------------------------------------------------------------------------
__global__ void transW(const float* __restrict__ Wq, const float* __restrict__ Wk,
                       const float* __restrict__ Wv, const float* __restrict__ Wo,
                       u16* __restrict__ WqkvT, u16* __restrict__ WoT) {
  __shared__ u16 tile[64][68];
  const int z = blockIdx.z;
  if (z == 1 && blockIdx.x >= 32) return;
  const int ox = blockIdx.x * 64;   // output-row base == source-col base
  const int oy = blockIdx.y * 64;   // source-row base
  const float* src; int scol, C; u16* dst;
  if (z == 0) {
    if (ox < 2048)      { src = Wq; scol = ox;        C = 2048; }
    else if (ox < 2560) { src = Wk; scol = ox - 2048; C = 512;  }
    else                { src = Wv; scol = ox - 2560; C = 512;  }
    dst = WqkvT;
  } else { src = Wo; scol = ox; C = 2048; dst = WoT; }
  const int t = threadIdx.x, lr = t >> 4, c4 = (t & 15) * 4;
#pragma unroll
  for (int p = 0; p < 4; ++p) {
    int r = p * 16 + lr;
    f32x4 v = *(const f32x4*)(src + (size_t)(oy + r) * C + scol + c4);
    s16x4 pk = {(short)f2b(v.x), (short)f2b(v.y), (short)f2b(v.z), (short)f2b(v.w)};
    *(s16x4*)(&tile[r][c4]) = pk;
  }
  __syncthreads();
#pragma unroll
  for (int q = 0; q < 4; ++q) {
    int oc = q * 16 + lr;
    s16x4 pk = {(short)tile[c4 + 0][oc], (short)tile[c4 + 1][oc],
                (short)tile[c4 + 2][oc], (short)tile[c4 + 3][oc]};
    *(s16x4*)(dst + (size_t)(ox + oc) * 2048 + oy + c4) = pk;
  }
}

// v slice of qkv (cols 2560..3071, stride 3072) -> vT[512][2048], bf16.
__global__ void transpose_v(const u16* __restrict__ qkv, u16* __restrict__ vT) {
  __shared__ u16 tile[64][68];
  const int bx = blockIdx.x * 64;   // v-col base (0..511)
  const int by = blockIdx.y * 64;   // token base
  const int t = threadIdx.x, lr = t >> 4, c4 = (t & 15) * 4;
#pragma unroll
  for (int p = 0; p < 4; ++p) {
    int r = p * 16 + lr;
    s16x4 v = *(const s16x4*)(qkv + (size_t)(by + r) * 3072 + 2560 + bx + c4);
    *(s16x4*)(&tile[r][c4]) = v;
  }
  __syncthreads();
#pragma unroll
  for (int q = 0; q < 4; ++q) {
    int oc = q * 16 + lr;
    s16x4 pk = {(short)tile[c4 + 0][oc], (short)tile[c4 + 1][oc],
                (short)tile[c4 + 2][oc], (short)tile[c4 + 3][oc]};
    *(s16x4*)(vT + (size_t)(bx + oc) * 2048 + by + c4) = pk;
  }
}

// ---------------------------------------------------------------------------
// 128x128 GEMM core (m97 structure): acc += A[M][K] @ Bt[N][K]^T, BK=32,
// async global_load_lds staging, 256 threads (2x2 waves of 64x64).
// ---------------------------------------------------------------------------
__device__ __forceinline__ void gemm_core(const u16* __restrict__ A,
                                          const u16* __restrict__ Bt,
                                          int K, int m0, int n0,
                                          f32x4 (*acc)[4], u16* As, u16* Bs) {
  const int t = threadIdx.x;
  const int wave = t >> 6, lane = t & 63, quad = lane >> 4, lc = lane & 15;
  const int wm = (wave >> 1) * 64, wn = (wave & 1) * 64;
  for (int k0 = 0; k0 < K; k0 += 32) {
#pragma unroll
    for (int h = 0; h < 2; ++h) {
      int ch = h * 256 + t, row = ch >> 2, kc = (ch & 3) * 8;
      gl_lds16(A  + (size_t)(m0 + row) * K + k0 + kc, As + (size_t)(h * 256 + wave * 64) * 8);
      gl_lds16(Bt + (size_t)(n0 + row) * K + k0 + kc, Bs + (size_t)(h * 256 + wave * 64) * 8);
    }
    __syncthreads();
    s16x8 af[4], bfr[4];
#pragma unroll
    for (int i = 0; i < 4; ++i)
      af[i] = *(const s16x8*)(As + (wm + i * 16 + lc) * 32 + quad * 8);
#pragma unroll
    for (int j = 0; j < 4; ++j)
      bfr[j] = *(const s16x8*)(Bs + (wn + j * 16 + lc) * 32 + quad * 8);
#pragma unroll
    for (int i = 0; i < 4; ++i)
#pragma unroll
      for (int j = 0; j < 4; ++j)
        acc[i][j] = mfma_bf16(af[i], bfr[j], acc[i][j]);
    __syncthreads();
  }
}

// QKV GEMM + fused RoPE epilogue.  grid (24, 16).
__global__ __launch_bounds__(256, 2) void gemm_qkv(const u16* __restrict__ A,
                                                   const u16* __restrict__ Bt,
                                                   u16* __restrict__ C) {
  __shared__ __align__(16) u16 As[128 * 32];
  __shared__ __align__(16) u16 Bs[128 * 32];
  const int n0 = blockIdx.x * 128, m0 = blockIdx.y * 128;
  const int lane = threadIdx.x & 63, wave = threadIdx.x >> 6;
  const int quad = lane >> 4, lc = lane & 15;
  const int wm = (wave >> 1) * 64, wn = (wave & 1) * 64;
  const f32x4 z = {0.f, 0.f, 0.f, 0.f};
  f32x4 acc[4][4];
#pragma unroll
  for (int i = 0; i < 4; ++i)
#pragma unroll
    for (int j = 0; j < 4; ++j) acc[i][j] = z;
  gemm_core(A, Bt, 2048, m0, n0, acc, As, Bs);
#pragma unroll
  for (int j = 0; j < 4; ++j) {
    const int colbase = wn + j * 16;
    const bool rope = (n0 + colbase) < 2560;     // q|k cols get RoPE
    const int col = n0 + colbase + lc;
    const int ip = ((colbase + lc) & 127) >> 1;  // pair idx within head
    const float inv_freq = exp2f(-0.20762050593046014f * (float)ip);
#pragma unroll
    for (int i = 0; i < 4; ++i)
#pragma unroll
      for (int r = 0; r < 4; ++r) {
        float v = acc[i][j][r];
        float p = __shfl_xor(v, 1);
        float val = v;
        if (rope) {
          int token = m0 + wm + i * 16 + quad * 4 + r;
          float ang = (float)token * inv_freq;
          float sv, cv;
          sincosf(ang, &sv, &cv);
          val = (lc & 1) ? (p * sv + v * cv) : (v * cv - p * sv);
        }
        C[(size_t)(m0 + wm + i * 16 + quad * 4 + r) * 3072 + col] = f2b(val);
      }
  }
}

// Out GEMM (fp32 epilogue).  grid (16, 16).
__global__ __launch_bounds__(256, 2) void gemm_out(const u16* __restrict__ A,
                                                   const u16* __restrict__ Bt,
                                                   float* __restrict__ C) {
  __shared__ __align__(16) u16 As[128 * 32];
  __shared__ __align__(16) u16 Bs[128 * 32];
  const int n0 = blockIdx.x * 128, m0 = blockIdx.y * 128;
  const int lane = threadIdx.x & 63, wave = threadIdx.x >> 6;
  const int quad = lane >> 4, lc = lane & 15;
  const int wm = (wave >> 1) * 64, wn = (wave & 1) * 64;
  const f32x4 z = {0.f, 0.f, 0.f, 0.f};
  f32x4 acc[4][4];
#pragma unroll
  for (int i = 0; i < 4; ++i)
#pragma unroll
    for (int j = 0; j < 4; ++j) acc[i][j] = z;
  gemm_core(A, Bt, 2048, m0, n0, acc, As, Bs);
#pragma unroll
  for (int i = 0; i < 4; ++i)
#pragma unroll
    for (int j = 0; j < 4; ++j)
#pragma unroll
      for (int r = 0; r < 4; ++r)
        C[(size_t)(m0 + wm + i * 16 + quad * 4 + r) * 2048 + n0 + wn + j * 16 + lc] =
            acc[i][j][r];
}

// ---------------------------------------------------------------------------
// Attention v4: BQ=128, equal-work chunks (<=8 kv-tiles of 64 keys), K+V in
// LDS (reg-staged, padded), Q frags in regs, prefetch issued AFTER the stage
// barrier (drained ~free, one compute-phase later).  Ps wave-private.
// grid = 640 blocks: bid = head*40 + idx; idx -> (qt 0..15, chunk).
// ---------------------------------------------------------------------------
__global__ __launch_bounds__(256, 2) void attn_k(const u16* __restrict__ qkv,
                                                 const u16* __restrict__ vT,
                                                 u16* __restrict__ Opart,
                                                 float* __restrict__ Lpart) {
  const int bid = blockIdx.x;
  const int hq = bid / 40, idx = bid % 40;
  int qt, c;
  if (idx < 4)       { qt = idx;                          c = 0; }
  else if (idx < 12) { int w = idx - 4;  qt = 4 + (w >> 1);  c = w & 1; }
  else if (idx < 24) { int w = idx - 12; qt = 8 + w / 3;     c = w % 3; }
  else               { int w = idx - 24; qt = 12 + (w >> 2); c = w & 3; }
  const int s0 = c * 8;
  const int s1 = min(c * 8 + 8, 2 * qt + 2);

  const int kvh = hq & 3;
  const int qc0 = hq << 7, kc0 = 2048 + (kvh << 7), vr0 = kvh << 7;

  __shared__ __align__(16) u16 Ks[64 * 136];   // 17.4 KB [key][d]+pad
  __shared__ __align__(16) u16 Vs[128 * 72];   // 18.4 KB [d][key]+pad
  __shared__ __align__(16) u16 Ps[128 * 72];   // 18.4 KB wave-private rows

  const int t = threadIdx.x, wave = t >> 6, lane = t & 63;
  const int quad = lane >> 4, lc = lane & 15;
  const int kr = t >> 4, kc = (t & 15) * 8;    // K staging coords
  const int vr = t >> 3, vc = (t & 7) * 8;     // V staging coords

  // Q A-frags in regs: wave owns 32 q-rows (2 row-blocks of 16)
  s16x8 qf[2][4];
#pragma unroll
  for (int i = 0; i < 2; ++i)
#pragma unroll
    for (int ks = 0; ks < 4; ++ks)
      qf[i][ks] = *(const s16x8*)(qkv +
          (size_t)(qt * 128 + wave * 32 + i * 16 + lc) * 3072 +
          qc0 + ks * 32 + quad * 8);

  const f32x4 z = {0.f, 0.f, 0.f, 0.f};
  f32x4 oa[2][8];
#pragma unroll
  for (int i = 0; i < 2; ++i)
#pragma unroll
    for (int n = 0; n < 8; ++n) oa[i][n] = z;
  float Ls[2][4] = {{0.f, 0.f, 0.f, 0.f}, {0.f, 0.f, 0.f, 0.f}};
  const float scale2 = 0.12751744545f;  // 1/sqrt(128) * log2(e)

  s16x8 kpf[4], vpf[4];
  { // prefetch first tile
    const int j0 = s0 * 64;
#pragma unroll
    for (int p = 0; p < 4; ++p)
      kpf[p] = *(const s16x8*)(qkv + (size_t)(j0 + p * 16 + kr) * 3072 + kc0 + kc);
#pragma unroll
    for (int p = 0; p < 4; ++p)
      vpf[p] = *(const s16x8*)(vT + (size_t)(vr0 + p * 32 + vr) * 2048 + j0 + vc);
  }

  for (int tile = s0; tile < s1; ++tile) {
    const int j0 = tile * 64;
    __syncthreads();   // prev compute's LDS reads done; prefetch landed long ago
#pragma unroll
    for (int p = 0; p < 4; ++p)
      *(s16x8*)(Ks + (p * 16 + kr) * 136 + kc) = kpf[p];
#pragma unroll
    for (int p = 0; p < 4; ++p)
      *(s16x8*)(Vs + (p * 32 + vr) * 72 + vc) = vpf[p];
    __syncthreads();   // staged visible; nothing in vmcnt -> cheap drain
    if (tile + 1 < s1) {  // prefetch AFTER the barrier: in flight over compute
      const int j1 = j0 + 64;
#pragma unroll
      for (int p = 0; p < 4; ++p)
        kpf[p] = *(const s16x8*)(qkv + (size_t)(j1 + p * 16 + kr) * 3072 + kc0 + kc);
#pragma unroll
      for (int p = 0; p < 4; ++p)
        vpf[p] = *(const s16x8*)(vT + (size_t)(vr0 + p * 32 + vr) * 2048 + j1 + vc);
    }
    // S = Q K^T  (2 row-blocks x 4 key-blocks)
    f32x4 sa[2][4];
#pragma unroll
    for (int i = 0; i < 2; ++i)
#pragma unroll
      for (int n = 0; n < 4; ++n) sa[i][n] = z;
#pragma unroll
    for (int ks = 0; ks < 4; ++ks)
#pragma unroll
      for (int n = 0; n < 4; ++n) {
        s16x8 bf = *(const s16x8*)(Ks + (n * 16 + lc) * 136 + ks * 32 + quad * 8);
        sa[0][n] = mfma_bf16(qf[0][ks], bf, sa[0][n]);
        sa[1][n] = mfma_bf16(qf[1][ks], bf, sa[1][n]);
      }
    // mask + exp2 + Ps (wave-private rows) + row sums
#pragma unroll
    for (int i = 0; i < 2; ++i) {
      const int qrow_base = qt * 128 + wave * 32 + i * 16 + quad * 4;
#pragma unroll
      for (int n = 0; n < 4; ++n) {
        int jc = j0 + n * 16 + lc;
#pragma unroll
        for (int r = 0; r < 4; ++r) {
          float e = (jc <= qrow_base + r) ? exp2f(sa[i][n][r] * scale2) : 0.f;
          Ps[(wave * 32 + i * 16 + quad * 4 + r) * 72 + n * 16 + lc] = f2b(e);
          Ls[i][r] += e;
        }
      }
    }
    // O += P V  (same-wave Ps rows -> lgkm ordering suffices, no barrier)
#pragma unroll
    for (int ks = 0; ks < 2; ++ks)
#pragma unroll
      for (int i = 0; i < 2; ++i) {
        s16x8 af = *(const s16x8*)(Ps + (wave * 32 + i * 16 + lc) * 72 +
                                   ks * 32 + quad * 8);
#pragma unroll
        for (int n = 0; n < 8; ++n) {
          s16x8 bf = *(const s16x8*)(Vs + (n * 16 + lc) * 72 + ks * 32 + quad * 8);
          oa[i][n] = mfma_bf16(af, bf, oa[i][n]);
        }
      }
  }
  // quad-wide row-sum reduce; store raw partials
#pragma unroll
  for (int i = 0; i < 2; ++i)
#pragma unroll
    for (int r = 0; r < 4; ++r) {
      float s = Ls[i][r];
      s += __shfl_xor(s, 1);
      s += __shfl_xor(s, 2);
      s += __shfl_xor(s, 4);
      s += __shfl_xor(s, 8);
      Ls[i][r] = s;
    }
  u16* Ob = Opart + (size_t)bid * (128 * 128);
  if (lc == 0) {
#pragma unroll
    for (int i = 0; i < 2; ++i)
#pragma unroll
      for (int r = 0; r < 4; ++r)
        Lpart[(size_t)bid * 128 + wave * 32 + i * 16 + quad * 4 + r] = Ls[i][r];
  }
#pragma unroll
  for (int i = 0; i < 2; ++i)
#pragma unroll
    for (int n = 0; n < 8; ++n)
#pragma unroll
      for (int r = 0; r < 4; ++r)
        Ob[(wave * 32 + i * 16 + quad * 4 + r) * 128 + n * 16 + lc] =
            f2b(oa[i][n][r]);
}

// Combine <=4 chunk partials: ctx = sum(O)/sum(L), head slot kv*4+sg.
// grid (128, 16 heads).
__global__ void attn_combine(const u16* __restrict__ Opart,
                             const float* __restrict__ Lpart,
                             u16* __restrict__ ctx) {
  const int hq = blockIdx.y, kvh = hq & 3, sg = hq >> 2;
  const int lin = blockIdx.x * 256 + threadIdx.x;   // 0..32767
  const int token = lin >> 4, d8 = (lin & 15) << 3;
  const int qt = token >> 7, row = token & 127;
  const int tier = qt >> 2;
  const int btab[4] = {0, 4, 12, 24};
  const int base = hq * 40 + btab[tier] + (qt & 3) * (tier + 1);
  const int cnt = tier + 1;
  float acc[8] = {0.f, 0.f, 0.f, 0.f, 0.f, 0.f, 0.f, 0.f};
  float L = 0.f;
  for (int c = 0; c < cnt; ++c) {
    const int b = base + c;
    L += Lpart[(size_t)b * 128 + row];
    s16x8 o = *(const s16x8*)(Opart + (size_t)b * 16384 + row * 128 + d8);
#pragma unroll
    for (int i = 0; i < 8; ++i) acc[i] += b2f((u16)o[i]);
  }
  const float inv = 1.f / L;
  s16x8 out;
#pragma unroll
  for (int i = 0; i < 8; ++i) out[i] = (short)f2b(acc[i] * inv);
  *(s16x8*)(ctx + (size_t)token * 2048 + ((kvh * 4 + sg) << 7) + d8) = out;
}

// ---------------------------------------------------------------------------
extern "C" void kernel_launch(void* const* d_in, const int* in_sizes, int n_in,
                              void* d_out, int out_size, void* d_ws, size_t ws_size,
                              hipStream_t stream) {
  const float* x  = (const float*)d_in[0];
  const float* Wq = (const float*)d_in[1];
  const float* Wk = (const float*)d_in[2];
  const float* Wv = (const float*)d_in[3];
  const float* Wo = (const float*)d_in[4];

  // Layout: [qkvb 12M][vTb 2M][WoT 8M][ctxb 8M][Lpart .33M][Opart 21M aliases
  // xb(8M)+WqkvT(12M)+1M] — xb/WqkvT dead before attn_k writes Opart.
  char* w = (char*)d_ws;
  u16* qkvb   = (u16*)w;  w += (size_t)2048 * 3072 * 2;       // 12 MB
  u16* vTb    = (u16*)w;  w += (size_t)512 * 2048 * 2;        //  2 MB
  u16* WoT    = (u16*)w;  w += (size_t)2048 * 2048 * 2;       //  8 MB
  u16* ctxb   = (u16*)w;  w += (size_t)2048 * 2048 * 2;       //  8 MB
  float* Lpart= (float*)w; w += (size_t)640 * 128 * 4;        // .33 MB
  u16* Opart  = (u16*)w;                                       // 21 MB region:
  u16* xb     = (u16*)w;  w += (size_t)2048 * 2048 * 2;       //  (aliased)
  u16* WqkvT  = (u16*)w;  w += (size_t)3072 * 2048 * 2;       //  (aliased)
  w += (size_t)2 * 1024 * 1024;                                // Opart spill

  // 1) convert x, transpose+convert weights
  conv_x<<<2048, 256, 0, stream>>>(x, xb, 2048 * 2048);
  transW<<<dim3(48, 32, 2), 256, 0, stream>>>(Wq, Wk, Wv, Wo, WqkvT, WoT);

  // 2) fused QKV projection + RoPE epilogue (128x128 m97 tiles)
  gemm_qkv<<<dim3(24, 16), 256, 0, stream>>>(xb, WqkvT, qkvb);

  // 3) v -> vT for the PV MFMA B-operand
  transpose_v<<<dim3(8, 32), 256, 0, stream>>>(qkvb, vTb);

  // 4) chunked attention (v4) + combine   [Opart overwrites xb/WqkvT]
  attn_k<<<640, 256, 0, stream>>>(qkvb, vTb, Opart, Lpart);
  attn_combine<<<dim3(128, 16), 256, 0, stream>>>(Opart, Lpart, ctxb);

  // 5) output projection (fp32 out, 128x128 tiles)
  gemm_out<<<dim3(16, 16), 256, 0, stream>>>(ctxb, WoT, (float*)d_out);
}

// Round 9
// 239.279 us; speedup vs baseline: 1.3706x; 1.0582x over previous
//
#include <hip/hip_runtime.h>

typedef unsigned short u16;
typedef float f32x4 __attribute__((ext_vector_type(4)));
typedef short s16x8 __attribute__((ext_vector_type(8)));
typedef short s16x4 __attribute__((ext_vector_type(4)));

__device__ __forceinline__ u16 f2b(float f) {
  union { float f; unsigned u; } v; v.f = f;
  unsigned r = v.u + 0x7fffu + ((v.u >> 16) & 1u);
  return (u16)(r >> 16);
}
__device__ __forceinline__ float b2f(u16 b) {
  union { unsigned u; float f; } v; v.u = ((unsigned)b) << 16;
  return v.f;
}
__device__ __forceinline__ f32x4 mfma_bf16(s16x8 a, s16x8 b, f32x4 c) {
  return __builtin_amdgcn_mfma_f32_16x16x32_bf16(a, b, c, 0, 0, 0);
}
__device__ __forceinline__ void gl_lds16(const u16* g, u16* l) {
  __builtin_amdgcn_global_load_lds(
      (const __attribute__((address_space(1))) void*)g,
      (__attribute__((address_space(3))) void*)l, 16, 0, 0);
}

// ---------------------------------------------------------------------------
// x fp32 -> bf16
// ---------------------------------------------------------------------------
__global__ void conv_x(const float* __restrict__ in, u16* __restrict__ out, int n) {
  int i = (blockIdx.x * 256 + threadIdx.x) * 8;
  if (i >= n) return;
  f32x4 a = *(const f32x4*)(in + i);
  f32x4 b = *(const f32x4*)(in + i + 4);
  s16x8 o = {(short)f2b(a.x), (short)f2b(a.y), (short)f2b(a.z), (short)f2b(a.w),
             (short)f2b(b.x), (short)f2b(b.y), (short)f2b(b.z), (short)f2b(b.w)};
  *(s16x8*)(out + i) = o;
}

// ---------------------------------------------------------------------------
// Weight transpose+convert fp32->bf16, 64x64 tiles.
// ---------------------------------------------------------------------------
__global__ void transW_qkv(const float* __restrict__ Wq, const float* __restrict__ Wk,
                           const float* __restrict__ Wv, u16* __restrict__ WqkvT) {
  __shared__ u16 tile[64][68];
  const int ox = blockIdx.x * 64;   // output-row base == source-col base
  const int oy = blockIdx.y * 64;   // source-row base
  const float* src; int scol, C;
  if (ox < 2048)      { src = Wq; scol = ox;        C = 2048; }
  else if (ox < 2560) { src = Wk; scol = ox - 2048; C = 512;  }
  else                { src = Wv; scol = ox - 2560; C = 512;  }
  const int t = threadIdx.x, lr = t >> 4, c4 = (t & 15) * 4;
#pragma unroll
  for (int p = 0; p < 4; ++p) {
    int r = p * 16 + lr;
    f32x4 v = *(const f32x4*)(src + (size_t)(oy + r) * C + scol + c4);
    s16x4 pk = {(short)f2b(v.x), (short)f2b(v.y), (short)f2b(v.z), (short)f2b(v.w)};
    *(s16x4*)(&tile[r][c4]) = pk;
  }
  __syncthreads();
#pragma unroll
  for (int q = 0; q < 4; ++q) {
    int oc = q * 16 + lr;
    s16x4 pk = {(short)tile[c4 + 0][oc], (short)tile[c4 + 1][oc],
                (short)tile[c4 + 2][oc], (short)tile[c4 + 3][oc]};
    *(s16x4*)(WqkvT + (size_t)(ox + oc) * 2048 + oy + c4) = pk;
  }
}

__global__ void transW_o(const float* __restrict__ Wo, u16* __restrict__ WoT) {
  __shared__ u16 tile[64][68];
  const int ox = blockIdx.x * 64, oy = blockIdx.y * 64;
  const int t = threadIdx.x, lr = t >> 4, c4 = (t & 15) * 4;
#pragma unroll
  for (int p = 0; p < 4; ++p) {
    int r = p * 16 + lr;
    f32x4 v = *(const f32x4*)(Wo + (size_t)(oy + r) * 2048 + ox + c4);
    s16x4 pk = {(short)f2b(v.x), (short)f2b(v.y), (short)f2b(v.z), (short)f2b(v.w)};
    *(s16x4*)(&tile[r][c4]) = pk;
  }
  __syncthreads();
#pragma unroll
  for (int q = 0; q < 4; ++q) {
    int oc = q * 16 + lr;
    s16x4 pk = {(short)tile[c4 + 0][oc], (short)tile[c4 + 1][oc],
                (short)tile[c4 + 2][oc], (short)tile[c4 + 3][oc]};
    *(s16x4*)(WoT + (size_t)(ox + oc) * 2048 + oy + c4) = pk;
  }
}

// v slice of qkv (cols 2560..3071) -> vT[512][2048]
__global__ void transpose_v(const u16* __restrict__ qkv, u16* __restrict__ vT) {
  __shared__ u16 tile[64][68];
  const int bx = blockIdx.x * 64, by = blockIdx.y * 64;
  const int t = threadIdx.x, lr = t >> 4, c4 = (t & 15) * 4;
#pragma unroll
  for (int p = 0; p < 4; ++p) {
    int r = p * 16 + lr;
    s16x4 v = *(const s16x4*)(qkv + (size_t)(by + r) * 3072 + 2560 + bx + c4);
    *(s16x4*)(&tile[r][c4]) = v;
  }
  __syncthreads();
#pragma unroll
  for (int q = 0; q < 4; ++q) {
    int oc = q * 16 + lr;
    s16x4 pk = {(short)tile[c4 + 0][oc], (short)tile[c4 + 1][oc],
                (short)tile[c4 + 2][oc], (short)tile[c4 + 3][oc]};
    *(s16x4*)(vT + (size_t)(bx + oc) * 2048 + by + c4) = pk;
  }
}

// ---------------------------------------------------------------------------
// 128x128 GEMM core (m97 structure), K-range parametrized for split-K.
// ---------------------------------------------------------------------------
__device__ __forceinline__ void gemm_core(const u16* __restrict__ A,
                                          const u16* __restrict__ Bt,
                                          int kbeg, int kend, int K,
                                          int m0, int n0,
                                          f32x4 (*acc)[4], u16* As, u16* Bs) {
  const int t = threadIdx.x;
  const int wave = t >> 6, lane = t & 63, quad = lane >> 4, lc = lane & 15;
  const int wm = (wave >> 1) * 64, wn = (wave & 1) * 64;
  for (int k0 = kbeg; k0 < kend; k0 += 32) {
#pragma unroll
    for (int h = 0; h < 2; ++h) {
      int ch = h * 256 + t, row = ch >> 2, kc = (ch & 3) * 8;
      gl_lds16(A  + (size_t)(m0 + row) * K + k0 + kc, As + (size_t)(h * 256 + wave * 64) * 8);
      gl_lds16(Bt + (size_t)(n0 + row) * K + k0 + kc, Bs + (size_t)(h * 256 + wave * 64) * 8);
    }
    __syncthreads();
    s16x8 af[4], bfr[4];
#pragma unroll
    for (int i = 0; i < 4; ++i)
      af[i] = *(const s16x8*)(As + (wm + i * 16 + lc) * 32 + quad * 8);
#pragma unroll
    for (int j = 0; j < 4; ++j)
      bfr[j] = *(const s16x8*)(Bs + (wn + j * 16 + lc) * 32 + quad * 8);
#pragma unroll
    for (int i = 0; i < 4; ++i)
#pragma unroll
      for (int j = 0; j < 4; ++j)
        acc[i][j] = mfma_bf16(af[i], bfr[j], acc[i][j]);
    __syncthreads();
  }
}

// QKV GEMM half: P[kh] = x @ WqkvT^T over K half.  grid (24,16,2).
__global__ __launch_bounds__(256, 2) void gemm_qkv_half(const u16* __restrict__ A,
                                                        const u16* __restrict__ Bt,
                                                        u16* __restrict__ P) {
  __shared__ __align__(16) u16 As[128 * 32];
  __shared__ __align__(16) u16 Bs[128 * 32];
  const int kh = blockIdx.z;
  const int n0 = blockIdx.x * 128, m0 = blockIdx.y * 128;
  const int lane = threadIdx.x & 63, wave = threadIdx.x >> 6;
  const int quad = lane >> 4, lc = lane & 15;
  const int wm = (wave >> 1) * 64, wn = (wave & 1) * 64;
  const f32x4 z = {0.f, 0.f, 0.f, 0.f};
  f32x4 acc[4][4];
#pragma unroll
  for (int i = 0; i < 4; ++i)
#pragma unroll
    for (int j = 0; j < 4; ++j) acc[i][j] = z;
  gemm_core(A, Bt, kh * 1024, kh * 1024 + 1024, 2048, m0, n0, acc, As, Bs);
  u16* Pk = P + (size_t)kh * (2048 * 3072);
#pragma unroll
  for (int i = 0; i < 4; ++i)
#pragma unroll
    for (int j = 0; j < 4; ++j)
#pragma unroll
      for (int r = 0; r < 4; ++r)
        Pk[(size_t)(m0 + wm + i * 16 + quad * 4 + r) * 3072 + n0 + wn + j * 16 + lc] =
            f2b(acc[i][j][r]);
}

// Reduce halves + RoPE (pairs are intra-vector) -> qkv bf16.  grid 3072.
__global__ void reduce_rope(const u16* __restrict__ P, u16* __restrict__ qkv) {
  const int lin = blockIdx.x * 256 + threadIdx.x;   // 0..786431
  const int row = lin / 384, c8 = (lin - row * 384) * 8;
  const u16* p0 = P + (size_t)row * 3072 + c8;
  s16x8 a = *(const s16x8*)p0;
  s16x8 b = *(const s16x8*)(p0 + 6291456);          // + 2048*3072
  float v[8];
#pragma unroll
  for (int i = 0; i < 8; ++i) v[i] = b2f((u16)a[i]) + b2f((u16)b[i]);
  if (c8 < 2560) {                                   // q|k cols get RoPE
#pragma unroll
    for (int h = 0; h < 4; ++h) {
      const int i = 2 * h;
      const int ip = ((c8 + i) & 127) >> 1;          // pair idx within head
      const float ang = (float)row * exp2f(-0.20762050593046014f * (float)ip);
      float sv, cv;
      sincosf(ang, &sv, &cv);
      const float e = v[i], o = v[i + 1];
      v[i]     = e * cv - o * sv;
      v[i + 1] = e * sv + o * cv;
    }
  }
  s16x8 o;
#pragma unroll
  for (int i = 0; i < 8; ++i) o[i] = (short)f2b(v[i]);
  *(s16x8*)(qkv + (size_t)row * 3072 + c8) = o;
}

// Out GEMM half: Po[kh] = ctx @ WoT^T over K half.  grid (16,16,2).
__global__ __launch_bounds__(256, 2) void gemm_out_half(const u16* __restrict__ A,
                                                        const u16* __restrict__ Bt,
                                                        u16* __restrict__ Po) {
  __shared__ __align__(16) u16 As[128 * 32];
  __shared__ __align__(16) u16 Bs[128 * 32];
  const int kh = blockIdx.z;
  const int n0 = blockIdx.x * 128, m0 = blockIdx.y * 128;
  const int lane = threadIdx.x & 63, wave = threadIdx.x >> 6;
  const int quad = lane >> 4, lc = lane & 15;
  const int wm = (wave >> 1) * 64, wn = (wave & 1) * 64;
  const f32x4 z = {0.f, 0.f, 0.f, 0.f};
  f32x4 acc[4][4];
#pragma unroll
  for (int i = 0; i < 4; ++i)
#pragma unroll
    for (int j = 0; j < 4; ++j) acc[i][j] = z;
  gemm_core(A, Bt, kh * 1024, kh * 1024 + 1024, 2048, m0, n0, acc, As, Bs);
  u16* Pk = Po + (size_t)kh * (2048 * 2048);
#pragma unroll
  for (int i = 0; i < 4; ++i)
#pragma unroll
    for (int j = 0; j < 4; ++j)
#pragma unroll
      for (int r = 0; r < 4; ++r)
        Pk[(size_t)(m0 + wm + i * 16 + quad * 4 + r) * 2048 + n0 + wn + j * 16 + lc] =
            f2b(acc[i][j][r]);
}

// Reduce out halves -> fp32 d_out.  grid 2048.
__global__ void reduce_out(const u16* __restrict__ Po, float* __restrict__ out) {
  const int lin = blockIdx.x * 256 + threadIdx.x;   // 0..524287
  const u16* p0 = Po + (size_t)lin * 8;
  s16x8 a = *(const s16x8*)p0;
  s16x8 b = *(const s16x8*)(p0 + 4194304);          // + 2048*2048
  f32x4 o0, o1;
#pragma unroll
  for (int i = 0; i < 4; ++i) o0[i] = b2f((u16)a[i]) + b2f((u16)b[i]);
#pragma unroll
  for (int i = 0; i < 4; ++i) o1[i] = b2f((u16)a[i + 4]) + b2f((u16)b[i + 4]);
  *(f32x4*)(out + (size_t)lin * 8) = o0;
  *(f32x4*)(out + (size_t)lin * 8 + 4) = o1;
}

// ---------------------------------------------------------------------------
// Attention v4 (unchanged from round 8 — validated).
// ---------------------------------------------------------------------------
__global__ __launch_bounds__(256, 2) void attn_k(const u16* __restrict__ qkv,
                                                 const u16* __restrict__ vT,
                                                 u16* __restrict__ Opart,
                                                 float* __restrict__ Lpart) {
  const int bid = blockIdx.x;
  const int hq = bid / 40, idx = bid % 40;
  int qt, c;
  if (idx < 4)       { qt = idx;                          c = 0; }
  else if (idx < 12) { int w = idx - 4;  qt = 4 + (w >> 1);  c = w & 1; }
  else if (idx < 24) { int w = idx - 12; qt = 8 + w / 3;     c = w % 3; }
  else               { int w = idx - 24; qt = 12 + (w >> 2); c = w & 3; }
  const int s0 = c * 8;
  const int s1 = min(c * 8 + 8, 2 * qt + 2);

  const int kvh = hq & 3;
  const int qc0 = hq << 7, kc0 = 2048 + (kvh << 7), vr0 = kvh << 7;

  __shared__ __align__(16) u16 Ks[64 * 136];
  __shared__ __align__(16) u16 Vs[128 * 72];
  __shared__ __align__(16) u16 Ps[128 * 72];

  const int t = threadIdx.x, wave = t >> 6, lane = t & 63;
  const int quad = lane >> 4, lc = lane & 15;
  const int kr = t >> 4, kc = (t & 15) * 8;
  const int vr = t >> 3, vc = (t & 7) * 8;

  s16x8 qf[2][4];
#pragma unroll
  for (int i = 0; i < 2; ++i)
#pragma unroll
    for (int ks = 0; ks < 4; ++ks)
      qf[i][ks] = *(const s16x8*)(qkv +
          (size_t)(qt * 128 + wave * 32 + i * 16 + lc) * 3072 +
          qc0 + ks * 32 + quad * 8);

  const f32x4 z = {0.f, 0.f, 0.f, 0.f};
  f32x4 oa[2][8];
#pragma unroll
  for (int i = 0; i < 2; ++i)
#pragma unroll
    for (int n = 0; n < 8; ++n) oa[i][n] = z;
  float Ls[2][4] = {{0.f, 0.f, 0.f, 0.f}, {0.f, 0.f, 0.f, 0.f}};
  const float scale2 = 0.12751744545f;

  s16x8 kpf[4], vpf[4];
  {
    const int j0 = s0 * 64;
#pragma unroll
    for (int p = 0; p < 4; ++p)
      kpf[p] = *(const s16x8*)(qkv + (size_t)(j0 + p * 16 + kr) * 3072 + kc0 + kc);
#pragma unroll
    for (int p = 0; p < 4; ++p)
      vpf[p] = *(const s16x8*)(vT + (size_t)(vr0 + p * 32 + vr) * 2048 + j0 + vc);
  }

  for (int tile = s0; tile < s1; ++tile) {
    const int j0 = tile * 64;
    __syncthreads();
#pragma unroll
    for (int p = 0; p < 4; ++p)
      *(s16x8*)(Ks + (p * 16 + kr) * 136 + kc) = kpf[p];
#pragma unroll
    for (int p = 0; p < 4; ++p)
      *(s16x8*)(Vs + (p * 32 + vr) * 72 + vc) = vpf[p];
    __syncthreads();
    if (tile + 1 < s1) {
      const int j1 = j0 + 64;
#pragma unroll
      for (int p = 0; p < 4; ++p)
        kpf[p] = *(const s16x8*)(qkv + (size_t)(j1 + p * 16 + kr) * 3072 + kc0 + kc);
#pragma unroll
      for (int p = 0; p < 4; ++p)
        vpf[p] = *(const s16x8*)(vT + (size_t)(vr0 + p * 32 + vr) * 2048 + j1 + vc);
    }
    f32x4 sa[2][4];
#pragma unroll
    for (int i = 0; i < 2; ++i)
#pragma unroll
      for (int n = 0; n < 4; ++n) sa[i][n] = z;
#pragma unroll
    for (int ks = 0; ks < 4; ++ks)
#pragma unroll
      for (int n = 0; n < 4; ++n) {
        s16x8 bf = *(const s16x8*)(Ks + (n * 16 + lc) * 136 + ks * 32 + quad * 8);
        sa[0][n] = mfma_bf16(qf[0][ks], bf, sa[0][n]);
        sa[1][n] = mfma_bf16(qf[1][ks], bf, sa[1][n]);
      }
#pragma unroll
    for (int i = 0; i < 2; ++i) {
      const int qrow_base = qt * 128 + wave * 32 + i * 16 + quad * 4;
#pragma unroll
      for (int n = 0; n < 4; ++n) {
        int jc = j0 + n * 16 + lc;
#pragma unroll
        for (int r = 0; r < 4; ++r) {
          float e = (jc <= qrow_base + r) ? exp2f(sa[i][n][r] * scale2) : 0.f;
          Ps[(wave * 32 + i * 16 + quad * 4 + r) * 72 + n * 16 + lc] = f2b(e);
          Ls[i][r] += e;
        }
      }
    }
#pragma unroll
    for (int ks = 0; ks < 2; ++ks)
#pragma unroll
      for (int i = 0; i < 2; ++i) {
        s16x8 af = *(const s16x8*)(Ps + (wave * 32 + i * 16 + lc) * 72 +
                                   ks * 32 + quad * 8);
#pragma unroll
        for (int n = 0; n < 8; ++n) {
          s16x8 bf = *(const s16x8*)(Vs + (n * 16 + lc) * 72 + ks * 32 + quad * 8);
          oa[i][n] = mfma_bf16(af, bf, oa[i][n]);
        }
      }
  }
#pragma unroll
  for (int i = 0; i < 2; ++i)
#pragma unroll
    for (int r = 0; r < 4; ++r) {
      float s = Ls[i][r];
      s += __shfl_xor(s, 1);
      s += __shfl_xor(s, 2);
      s += __shfl_xor(s, 4);
      s += __shfl_xor(s, 8);
      Ls[i][r] = s;
    }
  u16* Ob = Opart + (size_t)bid * (128 * 128);
  if (lc == 0) {
#pragma unroll
    for (int i = 0; i < 2; ++i)
#pragma unroll
      for (int r = 0; r < 4; ++r)
        Lpart[(size_t)bid * 128 + wave * 32 + i * 16 + quad * 4 + r] = Ls[i][r];
  }
#pragma unroll
  for (int i = 0; i < 2; ++i)
#pragma unroll
    for (int n = 0; n < 8; ++n)
#pragma unroll
      for (int r = 0; r < 4; ++r)
        Ob[(wave * 32 + i * 16 + quad * 4 + r) * 128 + n * 16 + lc] =
            f2b(oa[i][n][r]);
}

__global__ void attn_combine(const u16* __restrict__ Opart,
                             const float* __restrict__ Lpart,
                             u16* __restrict__ ctx) {
  const int hq = blockIdx.y, kvh = hq & 3, sg = hq >> 2;
  const int lin = blockIdx.x * 256 + threadIdx.x;
  const int token = lin >> 4, d8 = (lin & 15) << 3;
  const int qt = token >> 7, row = token & 127;
  const int tier = qt >> 2;
  const int btab[4] = {0, 4, 12, 24};
  const int base = hq * 40 + btab[tier] + (qt & 3) * (tier + 1);
  const int cnt = tier + 1;
  float acc[8] = {0.f, 0.f, 0.f, 0.f, 0.f, 0.f, 0.f, 0.f};
  float L = 0.f;
  for (int c = 0; c < cnt; ++c) {
    const int b = base + c;
    L += Lpart[(size_t)b * 128 + row];
    s16x8 o = *(const s16x8*)(Opart + (size_t)b * 16384 + row * 128 + d8);
#pragma unroll
    for (int i = 0; i < 8; ++i) acc[i] += b2f((u16)o[i]);
  }
  const float inv = 1.f / L;
  s16x8 out;
#pragma unroll
  for (int i = 0; i < 8; ++i) out[i] = (short)f2b(acc[i] * inv);
  *(s16x8*)(ctx + (size_t)token * 2048 + ((kvh * 4 + sg) << 7) + d8) = out;
}

// ---------------------------------------------------------------------------
extern "C" void kernel_launch(void* const* d_in, const int* in_sizes, int n_in,
                              void* d_out, int out_size, void* d_ws, size_t ws_size,
                              hipStream_t stream) {
  const float* x  = (const float*)d_in[0];
  const float* Wq = (const float*)d_in[1];
  const float* Wk = (const float*)d_in[2];
  const float* Wv = (const float*)d_in[3];
  const float* Wo = (const float*)d_in[4];

  // Workspace choreography (peak ~50.3 MB; 52.4 MB proven available in R3):
  //  [0 .. 8.39M)    xb          -> later qkvb (12.58M) -> later WoT (8.39M)
  //  [8.39 .. 20.97) WqkvT       -> later vTb@12.58 (2.1M) + Lpart@14.68 (.33M)
  //  [20.97 .. 46.14) Pq0|Pq1    -> later Opart (20.97M) -> later Po0|Po1 (16.8M)
  //  [41.94 .. 50.33) ctxb (8.39M, starts exactly at Opart end)
  char* base = (char*)d_ws;
  u16*   xb    = (u16*)(base);
  u16*   qkvb  = (u16*)(base);                       // aliases xb+WqkvT head
  u16*   WoT   = (u16*)(base);                       // aliases qkvb (dead)
  u16*   WqkvT = (u16*)(base + 8388608);
  u16*   vTb   = (u16*)(base + 12582912);            // aliases WqkvT (dead)
  float* Lpart = (float*)(base + 14680064);
  u16*   Pq    = (u16*)(base + 20971520);            // 2 x 12.58M
  u16*   Opart = (u16*)(base + 20971520);            // aliases Pq (dead)
  u16*   Po    = (u16*)(base + 20971520);            // aliases Opart (dead)
  u16*   ctxb  = (u16*)(base + 41943040);

  // 1) convert x; transpose qkv weights
  conv_x<<<2048, 256, 0, stream>>>(x, xb, 2048 * 2048);
  transW_qkv<<<dim3(48, 32), 256, 0, stream>>>(Wq, Wk, Wv, WqkvT);

  // 2) split-K QKV projection -> bf16 partials -> reduce + RoPE
  gemm_qkv_half<<<dim3(24, 16, 2), 256, 0, stream>>>(xb, WqkvT, Pq);
  reduce_rope<<<3072, 256, 0, stream>>>(Pq, qkvb);

  // 3) v -> vT
  transpose_v<<<dim3(8, 32), 256, 0, stream>>>(qkvb, vTb);

  // 4) chunked attention + combine   [Opart overwrites Pq]
  attn_k<<<640, 256, 0, stream>>>(qkvb, vTb, Opart, Lpart);
  attn_combine<<<dim3(128, 16), 256, 0, stream>>>(Opart, Lpart, ctxb);

  // 5) transpose Wo (qkvb dead now), split-K out projection, reduce -> fp32
  transW_o<<<dim3(32, 32), 256, 0, stream>>>(Wo, WoT);
  gemm_out_half<<<dim3(16, 16, 2), 256, 0, stream>>>(ctxb, WoT, Po);
  reduce_out<<<2048, 256, 0, stream>>>(Po, (float*)d_out);
}